// Round 1
// baseline (479.306 us; speedup 1.0000x reference)
//
#include <hip/hip_runtime.h>

// Problem: conv2d NCHW fp32: X[32,64,112,112] * W[128,64,3,3], pad=1, stride=1
//          -> out[32,128,112,112] fp32.
// Strategy: bf16 MFMA implicit GEMM. M=128 filters, N=112 (one output row/block),
// K=576 (c-major inside each of 9 kernel offsets). Input rows staged to LDS once
// per block; weights pre-transposed to [off][f][c] bf16 and read straight from
// global (L2-hot) -> zero barriers in the K-loop.

typedef __attribute__((ext_vector_type(8))) __bf16 bf16x8;
typedef __attribute__((ext_vector_type(4))) float  f32x4;

__device__ __forceinline__ unsigned short f2bf(float f) {
    unsigned u = __builtin_bit_cast(unsigned, f);
    u += 0x7FFF + ((u >> 16) & 1);          // round-to-nearest-even
    return (unsigned short)(u >> 16);
}

// ---- prep: W[f][c][kh][kw] fp32 -> wsA[off][f][c] bf16 (off = kh*3+kw) ----
__global__ void prep_weights(const float* __restrict__ flt,
                             unsigned short* __restrict__ wsA) {
    int idx = blockIdx.x * 256 + threadIdx.x;   // grid covers exactly 9*128*64
    if (idx >= 9 * 128 * 64) return;
    int off = idx >> 13;          // /8192
    int f   = (idx >> 6) & 127;
    int c   = idx & 63;
    wsA[idx] = f2bf(flt[(f * 64 + c) * 9 + off]);
}

// ---- main conv kernel: one block per (b, h); 256 thr = 4 waves ----
// Wave w computes filters [w*32, w*32+32) x all 112 output columns.
__global__ __launch_bounds__(256, 3)
void conv_mfma(const float* __restrict__ x,
               const unsigned short* __restrict__ wsA,
               float* __restrict__ out) {
    // Bs[kh][w'][c]: w' in [0,114) = input col (w'-1) with zero halo at 0,113.
    // stride 72 (144 B): 16B-aligned ds_read_b128, 2-way bank alias (free).
    __shared__ __align__(16) unsigned short Bs[3 * 114 * 72];

    const int tid = threadIdx.x;
    // XCD-aware swizzle: blocks id%8 share an XCD; give each XCD a contiguous
    // h-chunk so the 3-row input halo is L2-reused across neighboring h.
    const int id  = blockIdx.x;
    const int xcd = id & 7;
    const int s   = id >> 3;          // [0,448)
    const int b   = s / 14;           // [0,32)
    const int hh  = s - b * 14;       // [0,14)
    const int h   = xcd * 14 + hh;    // [0,112)

    // ---- stage 3 input rows (h-1..h+1), all 64 channels, into LDS ----
    for (int idx = tid; idx < 3 * 64 * 114; idx += 256) {
        int kh  = idx / 7296;             // 64*114
        int rem = idx - kh * 7296;
        int c   = rem / 114;
        int wp  = rem - c * 114;          // w' in [0,114)
        int hr  = h + kh - 1;
        int xw  = wp - 1;
        float v = 0.f;
        if ((unsigned)hr < 112u && (unsigned)xw < 112u)
            v = x[(((size_t)b * 64 + c) * 112 + hr) * 112 + xw];
        Bs[(kh * 114 + wp) * 72 + c] = f2bf(v);
    }
    __syncthreads();   // the only barrier in the kernel

    const int lane  = tid & 63;
    const int wid   = tid >> 6;
    const int q     = lane >> 4;
    const int l16   = lane & 15;
    const int wbase = wid * 32;           // wave's filter base

    f32x4 acc[2][7];
#pragma unroll
    for (int mt = 0; mt < 2; ++mt)
#pragma unroll
        for (int nt = 0; nt < 7; ++nt)
            acc[mt][nt] = {0.f, 0.f, 0.f, 0.f};

    for (int off = 0; off < 9; ++off) {
        const int kh = off / 3;
        const int kw = off - kh * 3;
        // A-frag source: wsA[off][f = wbase + l16 (+16)][c = cs*32 + q*8 + j]
        const unsigned short* wA = wsA + off * 8192 + (wbase + l16) * 64 + q * 8;
        const int brow = (kh * 114 + kw + l16) * 72 + q * 8;
#pragma unroll
        for (int cs = 0; cs < 2; ++cs) {
            bf16x8 a0 = *(const bf16x8*)(wA + cs * 32);
            bf16x8 a1 = *(const bf16x8*)(wA + 16 * 64 + cs * 32);
#pragma unroll
            for (int nt = 0; nt < 7; ++nt) {
                bf16x8 bf = *(const bf16x8*)(&Bs[brow + nt * 1152 + cs * 32]);
                acc[0][nt] = __builtin_amdgcn_mfma_f32_16x16x32_bf16(a0, bf, acc[0][nt], 0, 0, 0);
                acc[1][nt] = __builtin_amdgcn_mfma_f32_16x16x32_bf16(a1, bf, acc[1][nt], 0, 0, 0);
            }
        }
    }

    // ---- epilogue: D col = l16 (w), row = q*4+r (f within 16-tile) ----
#pragma unroll
    for (int mt = 0; mt < 2; ++mt) {
#pragma unroll
        for (int nt = 0; nt < 7; ++nt) {
            int f = wbase + mt * 16 + q * 4;
            int w = nt * 16 + l16;
            float* o = out + (((size_t)b * 128 + f) * 112 + h) * 112 + w;
#pragma unroll
            for (int r = 0; r < 4; ++r)
                o[(size_t)r * 12544] = acc[mt][nt][r];
        }
    }
}

extern "C" void kernel_launch(void* const* d_in, const int* in_sizes, int n_in,
                              void* d_out, int out_size, void* d_ws, size_t ws_size,
                              hipStream_t stream) {
    const float* x   = (const float*)d_in[0];   // dataset [32,64,112,112]
    const float* flt = (const float*)d_in[1];   // filters [128,64,3,3]
    float* out = (float*)d_out;
    unsigned short* wsA = (unsigned short*)d_ws;  // 9*128*64 bf16 = 147456 B

    hipLaunchKernelGGL(prep_weights, dim3(288), dim3(256), 0, stream, flt, wsA);
    hipLaunchKernelGGL(conv_mfma, dim3(3584), dim3(256), 0, stream, x, wsA, out);
}

// Round 2
// 349.983 us; speedup vs baseline: 1.3695x; 1.3695x over previous
//
#include <hip/hip_runtime.h>

// conv2d NCHW fp32: X[32,64,112,112] * W[128,64,3,3], pad=1 -> out[32,128,112,112].
// bf16 MFMA implicit GEMM. Block = 512 thr (8 waves) = 4 filter-groups x 2 output
// rows; one (b, h-pair) per block. Input rows h-1..h+2 staged to LDS as
// [kh-row][w'][c] bf16 with 128B row stride + XOR-swizzled 16B chunks
// (conflict-free b128 read AND write). Staging uses coalesced dwordx4 loads +
// in-register 8x8 shfl transpose. Weights pre-transposed to [off][f][c] bf16,
// A-frags read straight from global (L2-hot). No barriers in the K-loop.

typedef __attribute__((ext_vector_type(8))) __bf16 bf16x8;
typedef __attribute__((ext_vector_type(4))) float f32x4;
typedef __attribute__((ext_vector_type(4))) unsigned int u32x4;

#define ROWS_PER_KH 124
#define ROW_SHORTS 64  // 128 B per row

__device__ __forceinline__ unsigned short f2bf(float f) {
    unsigned u = __builtin_bit_cast(unsigned, f);
    u += 0x7FFF + ((u >> 16) & 1);  // round-to-nearest-even
    return (unsigned short)(u >> 16);
}

// ---- prep: W[f][c][kh][kw] fp32 -> wsA[off][f][c] bf16 (off = kh*3+kw) ----
__global__ void prep_weights(const float* __restrict__ flt,
                             unsigned short* __restrict__ wsA) {
    int idx = blockIdx.x * 256 + threadIdx.x;
    if (idx >= 9 * 128 * 64) return;
    int off = idx >> 13;
    int f   = (idx >> 6) & 127;
    int c   = idx & 63;
    wsA[idx] = f2bf(flt[(f * 64 + c) * 9 + off]);
}

__global__ __launch_bounds__(512, 4)
void conv_mfma(const float* __restrict__ x,
               const unsigned short* __restrict__ wsA,
               float* __restrict__ out) {
    // Bs: 4 kh-rows x 124 w'-rows x 64 shorts (chunk-XOR-swizzled). 63488 B.
    __shared__ __align__(16) unsigned short Bs[4 * ROWS_PER_KH * ROW_SHORTS];

    const int tid = threadIdx.x;
    const int id  = blockIdx.x;           // 1792 blocks
    const int xcd = id & 7;
    const int s   = id >> 3;              // [0,224)
    const int b   = s / 7;                // [0,32)
    const int hpl = s - b * 7;
    const int hp  = xcd * 7 + hpl;        // [0,56) — contiguous h-strip per XCD
    const int h0  = hp * 2;

    // ---- zero halo row wp=0 for each kh (wp=113 is zero-written by wo=14) ----
    if (tid < 32) {
        int kh = tid >> 3, cq = tid & 7;
        int R = kh * ROWS_PER_KH;
        int chunk = cq ^ (R & 7);
        *(u32x4*)&Bs[R * ROW_SHORTS + chunk * 8] = u32x4{0, 0, 0, 0};
    }

    // ---- stage input: units u = (wo[0,15), rp[0,4), cq[0,8)), 8 lanes/unit ----
    const int li   = tid & 7;
    const int unit = tid >> 3;            // [0,64)
    for (int it = 0; it < 8; ++it) {
        int u = it * 64 + unit;           // [0,512), valid < 480
        if (u < 480) {
            int wo = u >> 5;              // w-octet [0,15)
            int rc = u & 31;
            int rp = rc >> 3;             // input-row idx [0,4)
            int cq = rc & 7;              // c-octet
            int hr = h0 + rp - 1;
            int c  = cq * 8 + li;
            f32x4 f0 = {0.f, 0.f, 0.f, 0.f}, f1 = {0.f, 0.f, 0.f, 0.f};
            if ((unsigned)hr < 112u && wo < 14) {
                const float* src = x + (((size_t)b * 64 + c) * 112 + hr) * 112 + wo * 8;
                f0 = *(const f32x4*)src;
                f1 = *(const f32x4*)(src + 4);
            }
            float r[8] = {f0.x, f0.y, f0.z, f0.w, f1.x, f1.y, f1.z, f1.w};
            // 8x8 transpose among the 8 lanes of this unit (butterfly)
#pragma unroll
            for (int d = 1; d < 8; d <<= 1) {
#pragma unroll
                for (int jA = 0; jA < 8; ++jA) {
                    if (jA & d) continue;
                    int jB = jA | d;
                    float give = (li & d) ? r[jA] : r[jB];
                    float got  = __shfl_xor(give, d, 64);
                    if (li & d) r[jA] = got; else r[jB] = got;
                }
            }
            // lane li now holds c = cq*8 + j for w = wo*8 + li  -> row wp = w+1
            int R = rp * ROWS_PER_KH + wo * 8 + li + 1;
            int chunk = cq ^ (R & 7);
            unsigned pk[4];
#pragma unroll
            for (int j = 0; j < 4; ++j)
                pk[j] = (unsigned)f2bf(r[2 * j]) | ((unsigned)f2bf(r[2 * j + 1]) << 16);
            *(u32x4*)&Bs[R * ROW_SHORTS + chunk * 8] = u32x4{pk[0], pk[1], pk[2], pk[3]};
        }
    }
    __syncthreads();   // the only barrier

    // ---- K-loop: wave = 32 filters x 112 w of one output row ----
    const int lane = tid & 63;
    const int wid  = tid >> 6;            // 0..7
    const int fg   = wid & 3;             // filter group base = fg*32
    const int rr   = wid >> 2;            // output row h0 + rr
    const int q    = lane >> 4;
    const int l16  = lane & 15;
    const int h    = h0 + rr;

    f32x4 acc[2][7];
#pragma unroll
    for (int mt = 0; mt < 2; ++mt)
#pragma unroll
        for (int tw = 0; tw < 7; ++tw)
            acc[mt][tw] = {0.f, 0.f, 0.f, 0.f};

    const unsigned short* wA = wsA + (fg * 32 + l16) * 64 + q * 8;

#pragma unroll
    for (int off = 0; off < 9; ++off) {
        const int kh = off / 3;           // compile-time (unrolled)
        const int kw = off - kh * 3;
        const int Rbase = (rr + kh) * ROWS_PER_KH + kw;
#pragma unroll
        for (int cs = 0; cs < 2; ++cs) {
            bf16x8 a0 = *(const bf16x8*)(wA + off * 8192 + cs * 32);
            bf16x8 a1 = *(const bf16x8*)(wA + off * 8192 + 1024 + cs * 32);
            const int cq = cs * 4 + q;
#pragma unroll
            for (int tw = 0; tw < 7; ++tw) {
                int R = Rbase + tw * 16 + l16;
                int chunk = cq ^ (R & 7);
                bf16x8 bv = *(const bf16x8*)&Bs[R * ROW_SHORTS + chunk * 8];
                acc[0][tw] = __builtin_amdgcn_mfma_f32_16x16x32_bf16(a0, bv, acc[0][tw], 0, 0, 0);
                acc[1][tw] = __builtin_amdgcn_mfma_f32_16x16x32_bf16(a1, bv, acc[1][tw], 0, 0, 0);
            }
        }
    }

    // ---- epilogue: D col=l16 (w), row=q*4+r (f) ----
#pragma unroll
    for (int mt = 0; mt < 2; ++mt) {
#pragma unroll
        for (int tw = 0; tw < 7; ++tw) {
            int f = fg * 32 + mt * 16 + q * 4;
            int w = tw * 16 + l16;
            float* o = out + (((size_t)b * 128 + f) * 112 + h) * 112 + w;
#pragma unroll
            for (int r2 = 0; r2 < 4; ++r2)
                o[(size_t)r2 * 12544] = acc[mt][tw][r2];
        }
    }
}

extern "C" void kernel_launch(void* const* d_in, const int* in_sizes, int n_in,
                              void* d_out, int out_size, void* d_ws, size_t ws_size,
                              hipStream_t stream) {
    const float* x   = (const float*)d_in[0];   // dataset [32,64,112,112]
    const float* flt = (const float*)d_in[1];   // filters [128,64,3,3]
    float* out = (float*)d_out;
    unsigned short* wsA = (unsigned short*)d_ws;  // 147456 B

    hipLaunchKernelGGL(prep_weights, dim3(288), dim3(256), 0, stream, flt, wsA);
    hipLaunchKernelGGL(conv_mfma, dim3(1792), dim3(512), 0, stream, x, wsA, out);
}